// Round 8
// baseline (1482.152 us; speedup 1.0000x reference)
//
#include <hip/hip_runtime.h>
#include <math.h>

// Problem constants: B=32, T=64, N=128, D=64, E=5.  Time chunked: TC=8, 8 chunks.
// Pipeline: fused(c) = rec(c) || p4a(c+2) || p4b(c+1).  CX/GX* double-buffered by
// chunk parity.  Recurrence is SPLIT-PHASE:
//   GATE family  (512 blocks): (n, bq) = node n x 8 batches.  3x64x64 gate weights
//     LDS-resident for the whole chunk (zero weight re-streaming); own h kept in
//     registers across steps.  Consumes CH, produces h.
//   COMBH family (128 blocks): (b, qt) = batch b x 32 adj rows.  Stages h[b] once,
//     computes adj(t)@h rows, writes CH[n][b][:] (MALL), flags.
// Flags (first 4KB of ws): fH[bq*128+n] @ dword 0; fC[b*4+qt] @ dword 512.
// Step DAG: gate(t) <- combH(t) <- gate(t-1): no cycle; dead batches bump flags.
constexpr size_t WS_VV  = 1024;
constexpr size_t WS_TOT = 2048;
constexpr size_t WS_RS  = 8192;                  // 262144
constexpr size_t WS_WH  = 270336;                // 3*128*64*64 (Wr|Wu|Wc h-part)
constexpr size_t WS_WX  = 1843200;               // 3*128*65*64
constexpr size_t WS_BF  = 3440640;               // 3*128*64
constexpr size_t WS_H   = 3465216;               // 262144 (recurrent state; MALL)
constexpr size_t CXSZ   = 2129920;               // 128*256*65 per parity
constexpr size_t GXSZ   = 2097152;               // 128*8*32*64 per parity
constexpr size_t WS_CX0 = 3727360;               // 2 x CXSZ   [n][b*8+tl][65]
constexpr size_t WS_GXR0= 7987200;               // 2 x GXSZ   [n][tl][b][o]
constexpr size_t WS_GXU0= 12181504;
constexpr size_t WS_CXC0= 16375808;
constexpr size_t WS_CH  = 20570112;              // 128*32*64 = 262144  [n][b][k] (MALL)
// end = 20832256 floats = 79.5 MiB (same as the proven R0 footprint)

__device__ __forceinline__ float sigm(float x){ return 1.f/(1.f+expf(-x)); }

// MALL-coherent (agent-scope relaxed) 8B ld/st
__device__ __forceinline__ float2 ld2_mall(const float* p){
  union { unsigned long long u; float2 f; } cv;
  cv.u = __hip_atomic_load((const unsigned long long*)p, __ATOMIC_RELAXED,
                           __HIP_MEMORY_SCOPE_AGENT);
  return cv.f;
}
__device__ __forceinline__ void st2_mall(float* p, float a, float b){
  union { unsigned long long u; float2 f; } cv;
  cv.f = make_float2(a, b);
  __hip_atomic_store((unsigned long long*)p, cv.u, __ATOMIC_RELAXED,
                     __HIP_MEMORY_SCOPE_AGENT);
}

// ---------------- vv = relu(vpe@W1+b1)@W2+b2 ----------------
__global__ void k_vv(const float* __restrict__ vpe, const float* __restrict__ W1,
                     const float* __restrict__ b1, const float* __restrict__ W2,
                     const float* __restrict__ b2, float* __restrict__ ws){
  int n = blockIdx.x, tid = threadIdx.x;
  __shared__ float hid[128];
  if (tid < 128){
    float acc = b1[tid];
    for (int k=0;k<768;k++) acc = fmaf(vpe[n*768+k], W1[k*128+tid], acc);
    hid[tid] = fmaxf(acc, 0.f);
  }
  __syncthreads();
  if (tid < 5){
    float acc = b2[tid];
    for (int h=0;h<128;h++) acc = fmaf(hid[h], W2[h*5+tid], acc);
    ws[WS_VV + n*5 + tid] = acc;
  }
}

// ---------------- fold per-node weights: Wn = sum_e vv[n,e]*W[e] ----------------
__global__ void k_fold(const float* __restrict__ Wr, const float* __restrict__ Wu,
                       const float* __restrict__ Wc, const float* __restrict__ br,
                       const float* __restrict__ bu, const float* __restrict__ bc,
                       float* __restrict__ ws){
  int bid = blockIdx.x; int g = bid>>7; int n = bid&127;
  const float* W  = (g==0)?Wr:(g==1)?Wu:Wc;
  const float* bb = (g==0)?br:(g==1)?bu:bc;
  float v[5];
#pragma unroll
  for (int e=0;e<5;e++) v[e] = ws[WS_VV + n*5 + e];
  for (int idx=threadIdx.x; idx<129*64; idx+=256){
    int i = idx>>6, o = idx&63;
    float a = 0.f;
#pragma unroll
    for (int e=0;e<5;e++) a = fmaf(v[e], W[(e*129+i)*64+o], a);
    if (i < 65) ws[WS_WX + (size_t)(g*128+n)*4160 + i*64 + o] = a;
    else        ws[WS_WH + (size_t)(g*128+n)*4096 + (i-65)*64 + o] = a;
  }
  if (threadIdx.x < 64){
    int o = threadIdx.x; float a = 0.f;
#pragma unroll
    for (int e=0;e<5;e++) a = fmaf(v[e], bb[e*64+o], a);
    ws[WS_BF + (g*128+n)*64 + o] = a;
  }
}

// ---------------- tot[b,n] = sum_t mask ----------------
__global__ void k_tot(const float* __restrict__ mask, float* __restrict__ ws){
  int id = blockIdx.x*256 + threadIdx.x;     // 4096
  int b = id>>7, n = id&127;
  float s = 0.f;
  for (int t=0;t<64;t++) s += mask[(b*64+t)*128 + n];
  ws[WS_TOT + b*128 + n] = s;
}

// ---------------- rs = 0.5*tanh(avg/(tot+1)) ----------------
__global__ void k_rs(const float* __restrict__ avg, float* __restrict__ ws){
  int id = blockIdx.x*256 + threadIdx.x;     // 262144
  int b = id>>13, n = id&127;
  float tot = ws[WS_TOT + b*128 + n];
  ws[WS_RS + id] = 0.5f * tanhf(avg[id] / (tot + 1.f));
}

// ---------------- P4a body (chunk cc): combX = adj @ xtilde -> CX[cc&1] ----------------
__device__ void p4a_body(float* smem, const float* __restrict__ obs,
      const float* __restrict__ mask, const float* __restrict__ adjI,
      const float* __restrict__ rW, const int* __restrict__ lengths,
      float* __restrict__ ws, int cc, int rc){
  int b = rc>>3, tl = rc&7, t = cc*8 + tl;
  if (t >= lengths[b]) return;
  int rt = b*64 + t;
  float* xt   = smem;            // 64*68
  float* adjh = smem + 4352;     // 128*68
  float* rs_l = smem + 13056;    // 128
  float* m_l  = smem + 13184;    // 128
  int tid = threadIdx.x;
  if (tid < 128){ rs_l[tid] = ws[WS_RS + rt*128 + tid]; m_l[tid] = mask[rt*128 + tid]; }
  __syncthreads();
  int it = tid>>3, ft = tid&7, i0 = it*4, f0 = ft*8;
  float4 aL[4], aH[4]; float a64[4];
#pragma unroll
  for (int ii=0;ii<4;ii++){ aL[ii]=make_float4(0,0,0,0); aH[ii]=make_float4(0,0,0,0); a64[ii]=0.f; }
  for (int half=0; half<2; half++){
    __syncthreads();
    int j0 = half*64;
    for (int idx=tid; idx<4096; idx+=256){
      int jl = idx>>6, f = idx&63;
      xt[jl*68+f] = obs[(size_t)rt*8192 + (j0+jl)*64 + f];
    }
    if (tid < 64) xt[tid*68+64] = rs_l[j0+tid];
    for (int idx=tid; idx<8192; idx+=256){
      int i = idx>>6, jl = idx&63, j = j0+jl;
      float a;
      if (i == j) a = 1.f;
      else {
        int gi = i*128 + j;
        float dd = fabsf(rs_l[i] - rs_l[j]);
        a = adjI[gi] * (1.f - rW[gi]*dd) * m_l[i] * m_l[j];
      }
      adjh[i*68+jl] = a;
    }
    __syncthreads();
    for (int jb=0; jb<16; jb++){
      float4 av[4];
#pragma unroll
      for (int ii=0;ii<4;ii++) av[ii] = *(const float4*)&adjh[(i0+ii)*68 + jb*4];
#pragma unroll
      for (int jj=0;jj<4;jj++){
        int jl = jb*4 + jj;
        float4 xlo = *(const float4*)&xt[jl*68 + f0];
        float4 xhi = *(const float4*)&xt[jl*68 + f0 + 4];
        float xr = xt[jl*68 + 64];
#pragma unroll
        for (int ii=0;ii<4;ii++){
          float a = (jj==0)?av[ii].x:(jj==1)?av[ii].y:(jj==2)?av[ii].z:av[ii].w;
          aL[ii].x = fmaf(a, xlo.x, aL[ii].x); aL[ii].y = fmaf(a, xlo.y, aL[ii].y);
          aL[ii].z = fmaf(a, xlo.z, aL[ii].z); aL[ii].w = fmaf(a, xlo.w, aL[ii].w);
          aH[ii].x = fmaf(a, xhi.x, aH[ii].x); aH[ii].y = fmaf(a, xhi.y, aH[ii].y);
          aH[ii].z = fmaf(a, xhi.z, aH[ii].z); aH[ii].w = fmaf(a, xhi.w, aH[ii].w);
          a64[ii] = fmaf(a, xr, a64[ii]);
        }
      }
    }
  }
  size_t cxb = WS_CX0 + (size_t)(cc&1)*CXSZ;
#pragma unroll
  for (int ii=0;ii<4;ii++){
    int i = i0 + ii;
    size_t base = cxb + (size_t)i*16640 + (size_t)rc*65 + f0;
    ws[base+0]=aL[ii].x; ws[base+1]=aL[ii].y; ws[base+2]=aL[ii].z; ws[base+3]=aL[ii].w;
    ws[base+4]=aH[ii].x; ws[base+5]=aH[ii].y; ws[base+6]=aH[ii].z; ws[base+7]=aH[ii].w;
    if (ft == 0) ws[cxb + (size_t)i*16640 + (size_t)rc*65 + 64] = a64[ii];
  }
}

// ---------------- P4b body (chunk cc): per-node x-GEMMs -> GX*[cc&1] ----------------
__device__ void p4b_body(float* smem, const float* __restrict__ obs,
      const int* __restrict__ lengths, float* __restrict__ ws, int cc, int pbid){
  if (pbid >= 768) return;              // guard: only 3 gates x 128 nodes x 2 tiles
  int g = pbid >> 8; int r2 = pbid & 255; int n = r2 >> 1; int tile = r2 & 1;
  float* A  = smem;              // 128*69 = 8832
  float* Wl = smem + 8832;       // 4160
  float* bl = smem + 12992;      // 64
  int* slen = (int*)(smem + 13056); // 32
  int tid = threadIdx.x;
  if (tid < 32) slen[tid] = lengths[tid];
  for (int idx=tid; idx<4160; idx+=256) Wl[idx] = ws[WS_WX + (size_t)(g*128+n)*4160 + idx];
  if (tid < 64) bl[tid] = ws[WS_BF + (g*128+n)*64 + tid];
  size_t cxb = WS_CX0 + (size_t)(cc&1)*CXSZ;
  if (g < 2){
    const float* src = &ws[cxb + (size_t)n*16640 + (size_t)tile*8320];
    for (int idx=tid; idx<8320; idx+=256){
      int r = idx/65, f = idx - r*65;
      A[r*69+f] = src[idx];
    }
  } else {
    for (int idx=tid; idx<8320; idx+=256){
      int r = idx/65, f = idx - r*65;
      int grow = tile*128 + r;              // b*8+tl
      int gb = grow>>3, t = cc*8 + (grow&7);
      float v = (f < 64) ? obs[(size_t)(gb*64+t)*8192 + n*64 + f]
                         : ws[WS_RS + (gb*64+t)*128 + n];
      A[r*69+f] = v;
    }
  }
  __syncthreads();
  int rt8 = tid>>4, dq = tid&15;
  float4 acc[8];
#pragma unroll
  for (int rr=0;rr<8;rr++) acc[rr] = make_float4(0,0,0,0);
  for (int k=0;k<65;k++){
    float4 w = *(const float4*)&Wl[k*64 + dq*4];
#pragma unroll
    for (int rr=0;rr<8;rr++){
      float a = A[(rt8*8+rr)*69 + k];
      acc[rr].x = fmaf(a,w.x,acc[rr].x); acc[rr].y = fmaf(a,w.y,acc[rr].y);
      acc[rr].z = fmaf(a,w.z,acc[rr].z); acc[rr].w = fmaf(a,w.w,acc[rr].w);
    }
  }
  float4 b4 = *(const float4*)&bl[dq*4];
  size_t gxb = ((g==0)?WS_GXR0:(g==1)?WS_GXU0:WS_CXC0) + (size_t)(cc&1)*GXSZ;
#pragma unroll
  for (int rr=0;rr<8;rr++){
    int grow = tile*128 + rt8*8 + rr;
    int gb = grow>>3, gtl = grow&7;
    if (cc*8 + gtl < slen[gb]){
      float4 o; o.x=acc[rr].x+b4.x; o.y=acc[rr].y+b4.y; o.z=acc[rr].z+b4.z; o.w=acc[rr].w+b4.w;
      *(float4*)&ws[gxb + ((size_t)(n*8+gtl)*32 + gb)*64 + dq*4] = o;
    }
  }
}

// ---------------- GATE family: (n, bq) -- weights LDS-resident, h in registers ----
__device__ void gate_body(float* smem, const float* __restrict__ mask,
      const int* __restrict__ lengths, float* __restrict__ out,
      float* __restrict__ ws, int c){
  __builtin_amdgcn_s_setprio(1);
  unsigned* fH = (unsigned*)ws;          // [bq*128+n]
  unsigned* fC = (unsigned*)ws + 512;    // [b*4+qt]
  const int gid = blockIdx.x, tid = threadIdx.x;
  const int n = gid >> 2, bq = gid & 3;
  float* Wl  = smem;                 // 12288 : [g][k][f]
  float* chl = smem + 12288;         // 8*66
  float* h1l = smem + 12816;         // 8*66
  const int bl = tid >> 5, ln = tid & 31, f0 = ln*2;
  const int b  = bq*8 + bl;
  const int lenb = lengths[b];
  float* hbuf = &ws[WS_H];
  float* CH   = &ws[WS_CH];
  const int c0 = c*8;
  const size_t gq = (size_t)(c&1)*GXSZ;
  // load 3x64x64 gate weights once per launch (L2)
  for (int idx = tid; idx < 12288; idx += 256){
    int g = idx >> 12, r = idx & 4095;
    Wl[idx] = ws[WS_WH + ((size_t)(g*128+n))*4096 + r];
  }
  // own h in registers (exclusive writer) -- init h(c0-1)
  float2 hreg = ld2_mall(&hbuf[((size_t)b*128+n)*64 + f0]);
  __syncthreads();
  for (int t = c0; t < c0+8; t++){
    const int tl = t - c0;
    const bool alive = (t < lenb);                 // per-thread (batch-dependent)
    float msv = 0.f;
    float2 arv = make_float2(0,0), auv = arv, acv = arv;
    if (alive){
      msv = mask[(size_t)(b*64+t)*128 + n];
      size_t gof = ((size_t)(n*8+tl)*32 + b)*64 + f0;
      arv = *(const float2*)&ws[WS_GXR0 + gq + gof];
      auv = *(const float2*)&ws[WS_GXU0 + gq + gof];
      acv = *(const float2*)&ws[WS_CXC0 + gq + gof];
    }
    // wait for CH(t) from the 32 producers of this bq (dead blocks still flag)
    if (tid < 32){
      unsigned tgt = (unsigned)(t+1); int guard = 0;
      while (__hip_atomic_load(&fC[(bq*8 + (tid>>2))*4 + (tid&3)], __ATOMIC_RELAXED,
               __HIP_MEMORY_SCOPE_AGENT) < tgt && ++guard < (1<<20))
        __builtin_amdgcn_s_sleep(2);
    }
    __syncthreads();
    // stage CH rows (one 8B MALL load per thread)
    {
      float2 v = ld2_mall(&CH[(size_t)n*2048 + b*64 + f0]);
      chl[bl*66 + f0] = v.x; chl[bl*66 + f0 + 1] = v.y;
    }
    __syncthreads();
    // r/u gates from LDS-resident weights
#pragma unroll 4
    for (int k=0;k<64;k++){
      float cv = chl[bl*66 + k];
      float2 wr = *(const float2*)&Wl[k*64 + f0];
      float2 wu = *(const float2*)&Wl[4096 + k*64 + f0];
      arv.x = fmaf(cv,wr.x,arv.x); arv.y = fmaf(cv,wr.y,arv.y);
      auv.x = fmaf(cv,wu.x,auv.x); auv.y = fmaf(cv,wu.y,auv.y);
    }
    float2 r2, u2, h1;
    r2.x = sigm(arv.x); r2.y = sigm(arv.y);
    u2.x = sigm(auv.x); u2.y = sigm(auv.y);
    bool ob = alive && (msv > 0.f);
    h1.x = ob ? r2.x*hreg.x : hreg.x;
    h1.y = ob ? r2.y*hreg.y : hreg.y;
    h1l[bl*66 + f0] = h1.x; h1l[bl*66 + f0 + 1] = h1.y;
    __syncthreads();
    // candidate
#pragma unroll 4
    for (int k=0;k<64;k++){
      float hv = h1l[bl*66 + k];
      float2 wc = *(const float2*)&Wl[8192 + k*64 + f0];
      acv.x = fmaf(hv,wc.x,acv.x); acv.y = fmaf(hv,wc.y,acv.y);
    }
    float2 h2;
    float cdx = tanhf(acv.x), cdy = tanhf(acv.y);
    h2.x = ob ? (1.f-u2.x)*h1.x + u2.x*cdx : h1.x;
    h2.y = ob ? (1.f-u2.y)*h1.y + u2.y*cdy : h1.y;
    hreg = h2;
    if (alive){
      st2_mall(&hbuf[((size_t)b*128+n)*64 + f0], h2.x, h2.y);
      if (t == lenb-1)
        *(float2*)&out[((size_t)b*128+n)*64 + f0] = h2;
    }
    __syncthreads();   // h1l/chl reads done; all waves' stores drained at barrier
    asm volatile("s_waitcnt vmcnt(0)" ::: "memory");
    if (tid == 0)
      __hip_atomic_store(&fH[bq*128 + n], (unsigned)(t+1), __ATOMIC_RELAXED,
                         __HIP_MEMORY_SCOPE_AGENT);
  }
}

// ---------------- COMBH family: (b, qt) -- adj rows @ h -> CH ----------------
__device__ void combh_body(float* smem, const float* __restrict__ mask,
      const int* __restrict__ lengths, const float* __restrict__ adjI,
      const float* __restrict__ rWm, float* __restrict__ ws, int c){
  __builtin_amdgcn_s_setprio(1);
  unsigned* fH = (unsigned*)ws;
  unsigned* fC = (unsigned*)ws + 512;
  const int cid = blockIdx.x - 512, tid = threadIdx.x;
  const int b = cid >> 2, qt = cid & 3, I0 = qt*32;
  const int bq = b >> 3;
  float* hs   = smem;            // 8192
  float* adjT = smem + 8192;     // 128*36 = 4608  [j][il]
  float* rs_l = smem + 12800;    // 128
  float* m_l  = smem + 12928;    // 128
  const int lenb = lengths[b];
  const int rg = tid >> 5, f2 = (tid & 31)*2;    // rows rg*4..+4 (local), feats f2,f2+1
  float* hbuf = &ws[WS_H];
  float* CH   = &ws[WS_CH];
  const int c0 = c*8;
  for (int t = c0; t < c0+8; t++){
    if (t >= lenb){                 // dead batch: keep flags moving (block-uniform)
      if (tid == 0)
        __hip_atomic_store(&fC[b*4+qt], (unsigned)(t+1), __ATOMIC_RELAXED,
                           __HIP_MEMORY_SCOPE_AGENT);
      __syncthreads();
      continue;
    }
    if (tid < 128) rs_l[tid] = ws[WS_RS + (size_t)(b*64+t)*128 + tid];
    else           m_l[tid-128] = mask[(size_t)(b*64+t)*128 + (tid-128)];
    __syncthreads();
    for (int idx = tid; idx < 4096; idx += 256){
      int il = idx >> 7, j = idx & 127, I = I0 + il;
      float a;
      if (I == j) a = 1.f;
      else {
        int gi = I*128 + j;
        float dd = fabsf(rs_l[I] - rs_l[j]);
        a = adjI[gi]*(1.f - rWm[gi]*dd)*m_l[I]*m_l[j];
      }
      adjT[j*36 + il] = a;
    }
    // wait for h(t-1): all 128 gate flags of this bq
    if (t > 0 && tid < 128){
      unsigned tgt = (unsigned)t; int guard = 0;
      while (__hip_atomic_load(&fH[bq*128 + tid], __ATOMIC_RELAXED,
               __HIP_MEMORY_SCOPE_AGENT) < tgt && ++guard < (1<<20))
        __builtin_amdgcn_s_sleep(2);
    }
    __syncthreads();               // adjT ready + poll done
    // stage h[b]
#pragma unroll
    for (int k=0;k<16;k++){
      int p = tid + 256*k;
      *(float2*)&hs[2*p] = ld2_mall(&hbuf[(size_t)b*8192 + 2*p]);
    }
    __syncthreads();
    // GEMM: 4 rows x 2 feats per thread
    float2 acc[4] = {{0,0},{0,0},{0,0},{0,0}};
#pragma unroll 4
    for (int j=0;j<128;j++){
      float2 hv = *(const float2*)&hs[j*64 + f2];
      float4 a4 = *(const float4*)&adjT[j*36 + rg*4];
      acc[0].x = fmaf(a4.x,hv.x,acc[0].x); acc[0].y = fmaf(a4.x,hv.y,acc[0].y);
      acc[1].x = fmaf(a4.y,hv.x,acc[1].x); acc[1].y = fmaf(a4.y,hv.y,acc[1].y);
      acc[2].x = fmaf(a4.z,hv.x,acc[2].x); acc[2].y = fmaf(a4.z,hv.y,acc[2].y);
      acc[3].x = fmaf(a4.w,hv.x,acc[3].x); acc[3].y = fmaf(a4.w,hv.y,acc[3].y);
    }
#pragma unroll
    for (int rr=0;rr<4;rr++){
      int n = I0 + rg*4 + rr;
      st2_mall(&CH[(size_t)n*2048 + b*64 + f2], acc[rr].x, acc[rr].y);
    }
    __syncthreads();               // all waves' CH stores drained at barrier
    asm volatile("s_waitcnt vmcnt(0)" ::: "memory");
    if (tid == 0)
      __hip_atomic_store(&fC[b*4+qt], (unsigned)(t+1), __ATOMIC_RELAXED,
                         __HIP_MEMORY_SCOPE_AGENT);
  }
}

// ---------------- standalone precompute wrappers (pipeline prologue) ----------------
__global__ __launch_bounds__(256) void p4a_k(const float* __restrict__ obs,
      const float* __restrict__ mask, const float* __restrict__ adjI,
      const float* __restrict__ rW, const int* __restrict__ lengths,
      float* __restrict__ ws, int cc){
  __shared__ float smem[13344];
  p4a_body(smem, obs, mask, adjI, rW, lengths, ws, cc, blockIdx.x);
}
__global__ __launch_bounds__(256) void p4b_k(const float* __restrict__ obs,
      const int* __restrict__ lengths, float* __restrict__ ws, int cc){
  __shared__ float smem[13344];
  p4b_body(smem, obs, lengths, ws, cc, blockIdx.x);
}

// -------- fused: gate[512] | combH[128] | p4a(c+2)[256] | p4b(c+1)[768] ----------
__global__ __launch_bounds__(256) void kfused(const float* __restrict__ obs,
      const float* __restrict__ mask, const float* __restrict__ adjI,
      const float* __restrict__ rW, const int* __restrict__ lengths,
      float* __restrict__ out, float* __restrict__ ws, int c){
  __shared__ float smem[13344];
  int bid = blockIdx.x;
  if (bid < 512){
    gate_body(smem, mask, lengths, out, ws, c);
    return;
  }
  if (bid < 640){
    combh_body(smem, mask, lengths, adjI, rW, ws, c);
    return;
  }
  bool has4a = (c < 6);
  if (has4a && bid < 896){
    p4a_body(smem, obs, mask, adjI, rW, lengths, ws, c+2, bid-640);
    return;
  }
  int pb = bid - (has4a ? 896 : 640);
  p4b_body(smem, obs, lengths, ws, c+1, pb);
}

extern "C" void kernel_launch(void* const* d_in, const int* in_sizes, int n_in,
                              void* d_out, int out_size, void* d_ws, size_t ws_size,
                              hipStream_t stream){
  const float* obs  = (const float*)d_in[0];
  const float* maskp= (const float*)d_in[2];
  const int*   lens = (const int*)d_in[5];
  const float* avg  = (const float*)d_in[6];
  const float* vpe  = (const float*)d_in[7];
  const float* rW   = (const float*)d_in[8];
  const float* adjI = (const float*)d_in[9];
  const float* W1   = (const float*)d_in[10];
  const float* b1   = (const float*)d_in[11];
  const float* W2   = (const float*)d_in[12];
  const float* b2   = (const float*)d_in[13];
  const float* Wu   = (const float*)d_in[14];
  const float* bu   = (const float*)d_in[15];
  const float* Wr   = (const float*)d_in[16];
  const float* br   = (const float*)d_in[17];
  const float* Wc   = (const float*)d_in[18];
  const float* bc   = (const float*)d_in[19];
  float* out = (float*)d_out;
  float* ws  = (float*)d_ws;
  hipMemsetAsync(d_ws, 0, 4096, stream);
  hipMemsetAsync((char*)d_ws + WS_H*sizeof(float), 0, 262144*sizeof(float), stream);
  k_vv  <<<128, 256, 0, stream>>>(vpe, W1, b1, W2, b2, ws);
  k_fold<<<384, 256, 0, stream>>>(Wr, Wu, Wc, br, bu, bc, ws);
  k_tot <<<16,  256, 0, stream>>>(maskp, ws);
  k_rs  <<<1024,256, 0, stream>>>(avg, ws);
  // pipeline prologue
  p4a_k<<<256, 256, 0, stream>>>(obs, maskp, adjI, rW, lens, ws, 0);
  p4a_k<<<256, 256, 0, stream>>>(obs, maskp, adjI, rW, lens, ws, 1);
  p4b_k<<<768, 256, 0, stream>>>(obs, lens, ws, 0);
  // steady state: split-phase recurrence overlapped with next chunks' precompute
  for (int c = 0; c < 8; c++){
    int grid = (c <= 5) ? 1664 : (c == 6) ? 1408 : 640;
    kfused<<<grid, 256, 0, stream>>>(obs, maskp, adjI, rW, lens, out, ws, c);
  }
}

// Round 10
// 1399.928 us; speedup vs baseline: 1.0587x; 1.0587x over previous
//
#include <hip/hip_runtime.h>
#include <math.h>

// Problem constants: B=32, T=64, N=128, D=64, E=5.  Time chunked: TC=8, 8 chunks.
// Pipeline: fused(c) = krec(c) || p4a(c+2) || p4b(c+1).  CX/GX* double-buffered by
// chunk parity.  krec: proven R2 protocol (8 node-slices x 32 batches, MALL h
// exchange, 1 handoff/step).  Micro-cleanups vs R2: dead batches break (safe:
// consumers only poll while alive, and alive at chunk c+1 implies producers
// flagged through c0), poll wakeup s_sleep(1).
constexpr size_t WS_VV  = 1024;
constexpr size_t WS_TOT = 2048;
constexpr size_t WS_RS  = 8192;                  // 262144
constexpr size_t WS_WH  = 270336;                // 3*128*64*64 (Wr|Wu|Wc h-part)
constexpr size_t WS_WX  = 1843200;               // 3*128*65*64
constexpr size_t WS_BF  = 3440640;               // 3*128*64
constexpr size_t WS_H   = 3465216;               // 262144 (recurrent state; MALL)
constexpr size_t CXSZ   = 2129920;               // 128*256*65 per parity
constexpr size_t GXSZ   = 2097152;               // 128*8*32*64 per parity
constexpr size_t WS_CX0 = 3727360;               // 2 x CXSZ   [n][b*8+tl][65]
constexpr size_t WS_GXR0= 7987200;               // 2 x GXSZ   [n][tl][b][o]
constexpr size_t WS_GXU0= 12181504;
constexpr size_t WS_CXC0= 16375808;
// end = 20570112 floats = 78.5 MiB

__device__ __forceinline__ float sigm(float x){ return 1.f/(1.f+expf(-x)); }

// MALL-coherent (agent-scope relaxed) 8B ld/st
__device__ __forceinline__ float2 ld2_mall(const float* p){
  union { unsigned long long u; float2 f; } cv;
  cv.u = __hip_atomic_load((const unsigned long long*)p, __ATOMIC_RELAXED,
                           __HIP_MEMORY_SCOPE_AGENT);
  return cv.f;
}
__device__ __forceinline__ void st2_mall(float* p, float a, float b){
  union { unsigned long long u; float2 f; } cv;
  cv.f = make_float2(a, b);
  __hip_atomic_store((unsigned long long*)p, cv.u, __ATOMIC_RELAXED,
                     __HIP_MEMORY_SCOPE_AGENT);
}

// ---------------- vv = relu(vpe@W1+b1)@W2+b2 ----------------
__global__ void k_vv(const float* __restrict__ vpe, const float* __restrict__ W1,
                     const float* __restrict__ b1, const float* __restrict__ W2,
                     const float* __restrict__ b2, float* __restrict__ ws){
  int n = blockIdx.x, tid = threadIdx.x;
  __shared__ float hid[128];
  if (tid < 128){
    float acc = b1[tid];
    for (int k=0;k<768;k++) acc = fmaf(vpe[n*768+k], W1[k*128+tid], acc);
    hid[tid] = fmaxf(acc, 0.f);
  }
  __syncthreads();
  if (tid < 5){
    float acc = b2[tid];
    for (int h=0;h<128;h++) acc = fmaf(hid[h], W2[h*5+tid], acc);
    ws[WS_VV + n*5 + tid] = acc;
  }
}

// ---------------- fold per-node weights: Wn = sum_e vv[n,e]*W[e] ----------------
__global__ void k_fold(const float* __restrict__ Wr, const float* __restrict__ Wu,
                       const float* __restrict__ Wc, const float* __restrict__ br,
                       const float* __restrict__ bu, const float* __restrict__ bc,
                       float* __restrict__ ws){
  int bid = blockIdx.x; int g = bid>>7; int n = bid&127;
  const float* W  = (g==0)?Wr:(g==1)?Wu:Wc;
  const float* bb = (g==0)?br:(g==1)?bu:bc;
  float v[5];
#pragma unroll
  for (int e=0;e<5;e++) v[e] = ws[WS_VV + n*5 + e];
  for (int idx=threadIdx.x; idx<129*64; idx+=256){
    int i = idx>>6, o = idx&63;
    float a = 0.f;
#pragma unroll
    for (int e=0;e<5;e++) a = fmaf(v[e], W[(e*129+i)*64+o], a);
    if (i < 65) ws[WS_WX + (size_t)(g*128+n)*4160 + i*64 + o] = a;
    else        ws[WS_WH + (size_t)(g*128+n)*4096 + (i-65)*64 + o] = a;
  }
  if (threadIdx.x < 64){
    int o = threadIdx.x; float a = 0.f;
#pragma unroll
    for (int e=0;e<5;e++) a = fmaf(v[e], bb[e*64+o], a);
    ws[WS_BF + (g*128+n)*64 + o] = a;
  }
}

// ---------------- tot[b,n] = sum_t mask ----------------
__global__ void k_tot(const float* __restrict__ mask, float* __restrict__ ws){
  int id = blockIdx.x*256 + threadIdx.x;     // 4096
  int b = id>>7, n = id&127;
  float s = 0.f;
  for (int t=0;t<64;t++) s += mask[(b*64+t)*128 + n];
  ws[WS_TOT + b*128 + n] = s;
}

// ---------------- rs = 0.5*tanh(avg/(tot+1)) ----------------
__global__ void k_rs(const float* __restrict__ avg, float* __restrict__ ws){
  int id = blockIdx.x*256 + threadIdx.x;     // 262144
  int b = id>>13, n = id&127;
  float tot = ws[WS_TOT + b*128 + n];
  ws[WS_RS + id] = 0.5f * tanhf(avg[id] / (tot + 1.f));
}

// ---------------- P4a body (chunk cc): combX = adj @ xtilde -> CX[cc&1] ----------------
__device__ void p4a_body(float* smem, const float* __restrict__ obs,
      const float* __restrict__ mask, const float* __restrict__ adjI,
      const float* __restrict__ rW, const int* __restrict__ lengths,
      float* __restrict__ ws, int cc, int rc){
  int b = rc>>3, tl = rc&7, t = cc*8 + tl;
  if (t >= lengths[b]) return;
  int rt = b*64 + t;
  float* xt   = smem;            // 64*68
  float* adjh = smem + 4352;     // 128*68
  float* rs_l = smem + 13056;    // 128
  float* m_l  = smem + 13184;    // 128
  int tid = threadIdx.x;
  if (tid < 128){ rs_l[tid] = ws[WS_RS + rt*128 + tid]; m_l[tid] = mask[rt*128 + tid]; }
  __syncthreads();
  int it = tid>>3, ft = tid&7, i0 = it*4, f0 = ft*8;
  float4 aL[4], aH[4]; float a64[4];
#pragma unroll
  for (int ii=0;ii<4;ii++){ aL[ii]=make_float4(0,0,0,0); aH[ii]=make_float4(0,0,0,0); a64[ii]=0.f; }
  for (int half=0; half<2; half++){
    __syncthreads();
    int j0 = half*64;
    for (int idx=tid; idx<4096; idx+=256){
      int jl = idx>>6, f = idx&63;
      xt[jl*68+f] = obs[(size_t)rt*8192 + (j0+jl)*64 + f];
    }
    if (tid < 64) xt[tid*68+64] = rs_l[j0+tid];
    for (int idx=tid; idx<8192; idx+=256){
      int i = idx>>6, jl = idx&63, j = j0+jl;
      float a;
      if (i == j) a = 1.f;
      else {
        int gi = i*128 + j;
        float dd = fabsf(rs_l[i] - rs_l[j]);
        a = adjI[gi] * (1.f - rW[gi]*dd) * m_l[i] * m_l[j];
      }
      adjh[i*68+jl] = a;
    }
    __syncthreads();
    for (int jb=0; jb<16; jb++){
      float4 av[4];
#pragma unroll
      for (int ii=0;ii<4;ii++) av[ii] = *(const float4*)&adjh[(i0+ii)*68 + jb*4];
#pragma unroll
      for (int jj=0;jj<4;jj++){
        int jl = jb*4 + jj;
        float4 xlo = *(const float4*)&xt[jl*68 + f0];
        float4 xhi = *(const float4*)&xt[jl*68 + f0 + 4];
        float xr = xt[jl*68 + 64];
#pragma unroll
        for (int ii=0;ii<4;ii++){
          float a = (jj==0)?av[ii].x:(jj==1)?av[ii].y:(jj==2)?av[ii].z:av[ii].w;
          aL[ii].x = fmaf(a, xlo.x, aL[ii].x); aL[ii].y = fmaf(a, xlo.y, aL[ii].y);
          aL[ii].z = fmaf(a, xlo.z, aL[ii].z); aL[ii].w = fmaf(a, xlo.w, aL[ii].w);
          aH[ii].x = fmaf(a, xhi.x, aH[ii].x); aH[ii].y = fmaf(a, xhi.y, aH[ii].y);
          aH[ii].z = fmaf(a, xhi.z, aH[ii].z); aH[ii].w = fmaf(a, xhi.w, aH[ii].w);
          a64[ii] = fmaf(a, xr, a64[ii]);
        }
      }
    }
  }
  size_t cxb = WS_CX0 + (size_t)(cc&1)*CXSZ;
#pragma unroll
  for (int ii=0;ii<4;ii++){
    int i = i0 + ii;
    size_t base = cxb + (size_t)i*16640 + (size_t)rc*65 + f0;
    ws[base+0]=aL[ii].x; ws[base+1]=aL[ii].y; ws[base+2]=aL[ii].z; ws[base+3]=aL[ii].w;
    ws[base+4]=aH[ii].x; ws[base+5]=aH[ii].y; ws[base+6]=aH[ii].z; ws[base+7]=aH[ii].w;
    if (ft == 0) ws[cxb + (size_t)i*16640 + (size_t)rc*65 + 64] = a64[ii];
  }
}

// ---------------- P4b body (chunk cc): per-node x-GEMMs -> GX*[cc&1] ----------------
__device__ void p4b_body(float* smem, const float* __restrict__ obs,
      const int* __restrict__ lengths, float* __restrict__ ws, int cc, int pbid){
  if (pbid >= 768) return;              // guard
  int g = pbid >> 8; int r2 = pbid & 255; int n = r2 >> 1; int tile = r2 & 1;
  float* A  = smem;              // 128*69 = 8832
  float* Wl = smem + 8832;       // 4160
  float* bl = smem + 12992;      // 64
  int* slen = (int*)(smem + 13056); // 32
  int tid = threadIdx.x;
  if (tid < 32) slen[tid] = lengths[tid];
  for (int idx=tid; idx<4160; idx+=256) Wl[idx] = ws[WS_WX + (size_t)(g*128+n)*4160 + idx];
  if (tid < 64) bl[tid] = ws[WS_BF + (g*128+n)*64 + tid];
  size_t cxb = WS_CX0 + (size_t)(cc&1)*CXSZ;
  if (g < 2){
    const float* src = &ws[cxb + (size_t)n*16640 + (size_t)tile*8320];
    for (int idx=tid; idx<8320; idx+=256){
      int r = idx/65, f = idx - r*65;
      A[r*69+f] = src[idx];
    }
  } else {
    for (int idx=tid; idx<8320; idx+=256){
      int r = idx/65, f = idx - r*65;
      int grow = tile*128 + r;              // b*8+tl
      int gb = grow>>3, t = cc*8 + (grow&7);
      float v = (f < 64) ? obs[(size_t)(gb*64+t)*8192 + n*64 + f]
                         : ws[WS_RS + (gb*64+t)*128 + n];
      A[r*69+f] = v;
    }
  }
  __syncthreads();
  int rt8 = tid>>4, dq = tid&15;
  float4 acc[8];
#pragma unroll
  for (int rr=0;rr<8;rr++) acc[rr] = make_float4(0,0,0,0);
  for (int k=0;k<65;k++){
    float4 w = *(const float4*)&Wl[k*64 + dq*4];
#pragma unroll
    for (int rr=0;rr<8;rr++){
      float a = A[(rt8*8+rr)*69 + k];
      acc[rr].x = fmaf(a,w.x,acc[rr].x); acc[rr].y = fmaf(a,w.y,acc[rr].y);
      acc[rr].z = fmaf(a,w.z,acc[rr].z); acc[rr].w = fmaf(a,w.w,acc[rr].w);
    }
  }
  float4 b4 = *(const float4*)&bl[dq*4];
  size_t gxb = ((g==0)?WS_GXR0:(g==1)?WS_GXU0:WS_CXC0) + (size_t)(cc&1)*GXSZ;
#pragma unroll
  for (int rr=0;rr<8;rr++){
    int grow = tile*128 + rt8*8 + rr;
    int gb = grow>>3, gtl = grow&7;
    if (cc*8 + gtl < slen[gb]){
      float4 o; o.x=acc[rr].x+b4.x; o.y=acc[rr].y+b4.y; o.z=acc[rr].z+b4.z; o.w=acc[rr].w+b4.w;
      *(float4*)&ws[gxb + ((size_t)(n*8+gtl)*32 + gb)*64 + dq*4] = o;
    }
  }
}

// ---------------- Recurrent kernel (proven R2 protocol, micro-cleaned) ----------------
// 256 blocks; block (bA=bid>>3, s=bid&7) owns nodes s*16..s*16+16 of batch bA.
// ONE batch-local handoff/step via MALL; flags hfl[bA*8+s] monotone.
__device__ void krec_body(float* smem, const float* __restrict__ mask,
      const int* __restrict__ lengths, const float* __restrict__ adjI,
      const float* __restrict__ rWm, float* __restrict__ out,
      float* __restrict__ ws, int c){
  __builtin_amdgcn_s_setprio(1);           // recurrence is the critical path
  unsigned* hfl = (unsigned*)ws;           // hfl[bA*8+s] = completed steps (monotone)
  const int bid = blockIdx.x, tid = threadIdx.x;
  const int bA = bid>>3, s = bid&7, ns = s*16;
  float* hs   = smem;            // 8192  staged h[bA] [node][f]
  float* adjT = smem + 8192;     // 2560  adj [j][il] stride 20
  float* chT  = smem + 10752;    // 1088  combH exchange [n_local][k] s68
  float* hT   = smem + 11840;    // 1088  h1 exchange
  float* rs_l = smem + 12928;    // 128
  float* m_l  = smem + 13056;    // 128
  const int lenA = lengths[bA];
  const int ng = tid>>6, fA = tid&63;      // A-GEMM mapping: 4 rows x 1 feature
  const int nl = tid>>4, fq = tid&15;      // gate mapping: 1 node x 4 features
  const int n  = ns + nl;
  float* hbuf = &ws[WS_H];
  const float* wrg = &ws[WS_WH + (size_t)(0*128+n)*4096];
  const float* wug = &ws[WS_WH + (size_t)(1*128+n)*4096];
  const float* wcg = &ws[WS_WH + (size_t)(2*128+n)*4096];
  const int c0 = c*8;
  const size_t gq = (size_t)(c&1)*GXSZ;

  for (int t=c0; t<c0+8; t++){
    // Dead batch: exit the chunk entirely.  Safe: a consumer polls flags only
    // while alive (t < lenA, lenA shared by all 8 siblings), and a batch alive
    // at chunk c+1 had all its producers complete every step of chunk c.
    if (t >= lenA) break;
    // ---- step-known prework (overlaps siblings' previous-step production) ----
    if (tid < 128) rs_l[tid] = ws[WS_RS + (size_t)(bA*64+t)*128 + tid];
    else           m_l[tid-128] = mask[(size_t)(bA*64+t)*128 + (tid-128)];
    __syncthreads();
    for (int idx=tid; idx<2048; idx+=256){
      int j = idx&127, il = idx>>7, I = ns+il;
      float a;
      if (I == j) a = 1.f;
      else {
        int gi = I*128 + j;
        float dd = fabsf(rs_l[I] - rs_l[j]);
        a = adjI[gi]*(1.f - rWm[gi]*dd)*m_l[I]*m_l[j];
      }
      adjT[j*20 + il] = a;
    }
    const int tl = t - c0;
    size_t gof = ((size_t)(n*8+tl)*32 + bA)*64 + fq*4;
    float4 arv = *(const float4*)&ws[WS_GXR0 + gq + gof];   // x-parts (incl. bias)
    float4 auv = *(const float4*)&ws[WS_GXU0 + gq + gof];
    float4 acv = *(const float4*)&ws[WS_CXC0 + gq + gof];
    float  msv = m_l[n];
    // ---- wait for siblings' h(t-1) ----
    if (t > 0){
      if (tid < 8){
        unsigned tgt = (unsigned)t; int guard = 0;
        while (__hip_atomic_load(&hfl[bA*8 + tid], __ATOMIC_RELAXED,
                 __HIP_MEMORY_SCOPE_AGENT) < tgt && ++guard < (1<<20))
          __builtin_amdgcn_s_sleep(1);
      }
    }
    __syncthreads();     // adjT built + poll done
    // ---- stage full h[bA] into LDS (coalesced MALL 8B loads) ----
#pragma unroll
    for (int k=0;k<16;k++){
      int p = tid + 256*k;
      float2 v = ld2_mall(&hbuf[(size_t)bA*8192 + 2*p]);
      *(float2*)&hs[2*p] = v;
    }
    __syncthreads();
    // ---- combH rows: acc[r] = sum_j adj[I,j] * h[j, fA] ----
    float acc[4] = {0.f,0.f,0.f,0.f};
#pragma unroll 4
    for (int j=0;j<128;j++){
      float hv = hs[j*64 + fA];
      float4 a4 = *(const float4*)&adjT[j*20 + ng*4];
      acc[0] = fmaf(a4.x, hv, acc[0]);
      acc[1] = fmaf(a4.y, hv, acc[1]);
      acc[2] = fmaf(a4.z, hv, acc[2]);
      acc[3] = fmaf(a4.w, hv, acc[3]);
    }
#pragma unroll
    for (int r=0;r<4;r++) chT[(ng*4+r)*68 + fA] = acc[r];
    __syncthreads();
    // ---- r/u gates: += combH[n,:] @ Wh (L2-streamed weights) ----
#pragma unroll 4
    for (int k=0;k<64;k++){
      float cv = chT[nl*68 + k];
      float4 wr4 = *(const float4*)&wrg[k*64 + fq*4];
      float4 wu4 = *(const float4*)&wug[k*64 + fq*4];
      arv.x = fmaf(cv,wr4.x,arv.x); arv.y = fmaf(cv,wr4.y,arv.y);
      arv.z = fmaf(cv,wr4.z,arv.z); arv.w = fmaf(cv,wr4.w,arv.w);
      auv.x = fmaf(cv,wu4.x,auv.x); auv.y = fmaf(cv,wu4.y,auv.y);
      auv.z = fmaf(cv,wu4.z,auv.z); auv.w = fmaf(cv,wu4.w,auv.w);
    }
    float4 rr4, uu4, h1;
    rr4.x = sigm(arv.x); rr4.y = sigm(arv.y); rr4.z = sigm(arv.z); rr4.w = sigm(arv.w);
    uu4.x = sigm(auv.x); uu4.y = sigm(auv.y); uu4.z = sigm(auv.z); uu4.w = sigm(auv.w);
    float4 hown = *(const float4*)&hs[n*64 + fq*4];
    bool ob = msv > 0.f;
    h1.x = ob ? rr4.x*hown.x : hown.x;
    h1.y = ob ? rr4.y*hown.y : hown.y;
    h1.z = ob ? rr4.z*hown.z : hown.z;
    h1.w = ob ? rr4.w*hown.w : hown.w;
    *(float4*)&hT[nl*68 + fq*4] = h1;
    __syncthreads();
    // ---- candidate: += h1[n,:] @ Wc ----
#pragma unroll 4
    for (int k=0;k<64;k++){
      float hv1 = hT[nl*68 + k];
      float4 wc4 = *(const float4*)&wcg[k*64 + fq*4];
      acv.x = fmaf(hv1,wc4.x,acv.x); acv.y = fmaf(hv1,wc4.y,acv.y);
      acv.z = fmaf(hv1,wc4.z,acv.z); acv.w = fmaf(hv1,wc4.w,acv.w);
    }
    float4 cd, h2;
    cd.x = tanhf(acv.x); cd.y = tanhf(acv.y); cd.z = tanhf(acv.z); cd.w = tanhf(acv.w);
    h2.x = ob ? (1.f-uu4.x)*h1.x + uu4.x*cd.x : h1.x;
    h2.y = ob ? (1.f-uu4.y)*h1.y + uu4.y*cd.y : h1.y;
    h2.z = ob ? (1.f-uu4.z)*h1.z + uu4.z*cd.z : h1.z;
    h2.w = ob ? (1.f-uu4.w)*h1.w + uu4.w*cd.w : h1.w;
    float* hp = &hbuf[((size_t)bA*128 + n)*64 + fq*4];
    st2_mall(hp,   h2.x, h2.y);
    st2_mall(hp+2, h2.z, h2.w);
    if (t == lenA-1)
      *(float4*)&out[((size_t)bA*128 + n)*64 + fq*4] = h2;
    __syncthreads();   // everyone done with hs/chT/hT/rs_l/m_l before next iter
    asm volatile("s_waitcnt vmcnt(0)" ::: "memory");   // release: h stores visible
    if (tid == 0)
      __hip_atomic_store(&hfl[bid], (unsigned)(t+1), __ATOMIC_RELAXED,
                         __HIP_MEMORY_SCOPE_AGENT);
  }
}

// ---------------- standalone precompute wrappers (pipeline prologue) ----------------
__global__ __launch_bounds__(256) void p4a_k(const float* __restrict__ obs,
      const float* __restrict__ mask, const float* __restrict__ adjI,
      const float* __restrict__ rW, const int* __restrict__ lengths,
      float* __restrict__ ws, int cc){
  __shared__ float smem[13312];
  p4a_body(smem, obs, mask, adjI, rW, lengths, ws, cc, blockIdx.x);
}
__global__ __launch_bounds__(256) void p4b_k(const float* __restrict__ obs,
      const int* __restrict__ lengths, float* __restrict__ ws, int cc){
  __shared__ float smem[13312];
  p4b_body(smem, obs, lengths, ws, cc, blockIdx.x);
}

// ---------------- fused: krec(c) [256] || p4a(c+2) [256] || p4b(c+1) [768] --------
__global__ __launch_bounds__(256) void kfused(const float* __restrict__ obs,
      const float* __restrict__ mask, const float* __restrict__ adjI,
      const float* __restrict__ rW, const int* __restrict__ lengths,
      float* __restrict__ out, float* __restrict__ ws, int c){
  __shared__ float smem[13312];
  int bid = blockIdx.x;
  if (bid < 256){
    krec_body(smem, mask, lengths, adjI, rW, out, ws, c);
    return;
  }
  bool has4a = (c < 6);
  if (has4a && bid < 512){
    p4a_body(smem, obs, mask, adjI, rW, lengths, ws, c+2, bid-256);
    return;
  }
  int pb = bid - (has4a ? 512 : 256);
  p4b_body(smem, obs, lengths, ws, c+1, pb);
}

extern "C" void kernel_launch(void* const* d_in, const int* in_sizes, int n_in,
                              void* d_out, int out_size, void* d_ws, size_t ws_size,
                              hipStream_t stream){
  const float* obs  = (const float*)d_in[0];
  const float* maskp= (const float*)d_in[2];
  const int*   lens = (const int*)d_in[5];
  const float* avg  = (const float*)d_in[6];
  const float* vpe  = (const float*)d_in[7];
  const float* rW   = (const float*)d_in[8];
  const float* adjI = (const float*)d_in[9];
  const float* W1   = (const float*)d_in[10];
  const float* b1   = (const float*)d_in[11];
  const float* W2   = (const float*)d_in[12];
  const float* b2   = (const float*)d_in[13];
  const float* Wu   = (const float*)d_in[14];
  const float* bu   = (const float*)d_in[15];
  const float* Wr   = (const float*)d_in[16];
  const float* br   = (const float*)d_in[17];
  const float* Wc   = (const float*)d_in[18];
  const float* bc   = (const float*)d_in[19];
  float* out = (float*)d_out;
  float* ws  = (float*)d_ws;
  hipMemsetAsync(d_ws, 0, 4096, stream);
  hipMemsetAsync((char*)d_ws + WS_H*sizeof(float), 0, 262144*sizeof(float), stream);
  k_vv  <<<128, 256, 0, stream>>>(vpe, W1, b1, W2, b2, ws);
  k_fold<<<384, 256, 0, stream>>>(Wr, Wu, Wc, br, bu, bc, ws);
  k_tot <<<16,  256, 0, stream>>>(maskp, ws);
  k_rs  <<<1024,256, 0, stream>>>(avg, ws);
  // pipeline prologue
  p4a_k<<<256, 256, 0, stream>>>(obs, maskp, adjI, rW, lens, ws, 0);
  p4a_k<<<256, 256, 0, stream>>>(obs, maskp, adjI, rW, lens, ws, 1);
  p4b_k<<<768, 256, 0, stream>>>(obs, lens, ws, 0);
  // steady state: recurrence overlapped with next chunks' precompute
  for (int c = 0; c < 8; c++){
    int grid = (c <= 5) ? 1280 : (c == 6) ? 1024 : 256;
    kfused<<<grid, 256, 0, stream>>>(obs, maskp, adjI, rW, lens, out, ws, c);
  }
}